// Round 1
// baseline (267.991 us; speedup 1.0000x reference)
//
#include <hip/hip_runtime.h>
#include <hip/hip_bf16.h>

// out[t,n] = sum_k x[k,t] * W[k,n] + b[n]
// x: [256, 131072] f32 (K-major), W: [256, 256] f32, b: [256] f32
// out: [131072, 256] f32
//
// Strategy: split-bf16 MFMA (hi*hi + hi*lo + lo*hi), memory-bound target ~43us.

#define TOKENS 131072
#define KDIM   256
#define NDIM   256
#define BM     128   // tokens per block
#define BK     32    // k per LDS stage step
#define NSTEPS (KDIM / BK)   // 8

typedef __bf16 bf16x8 __attribute__((ext_vector_type(8)));
typedef float  f32x4  __attribute__((ext_vector_type(4)));
typedef unsigned short ushort8 __attribute__((ext_vector_type(8)));

__device__ __forceinline__ unsigned short f32_to_bf16_rne(float f) {
    unsigned int u = __builtin_bit_cast(unsigned int, f);
    u += 0x7fffu + ((u >> 16) & 1u);   // round-to-nearest-even (finite inputs)
    return (unsigned short)(u >> 16);
}
__device__ __forceinline__ float bf16_to_f32(unsigned short h) {
    unsigned int u = ((unsigned int)h) << 16;
    return __builtin_bit_cast(float, u);
}

// ---------------------------------------------------------------------------
// Prep: pack W into B-fragment order, split into hi/lo bf16.
// wp layout (ushort): hi region [0, 65536), lo region [65536, 131072)
// element ((ks*16 + ntg)*64 + lane)*8 + p  =  W[ks*32 + (lane>>4)*8 + p][ntg*16 + (lane&15)]
// ---------------------------------------------------------------------------
__global__ void prep_w_kernel(const float* __restrict__ W, unsigned short* __restrict__ wp) {
    int tid = blockIdx.x * 256 + threadIdx.x;   // 0..65535
    int p  = tid & 7;
    int l  = (tid >> 3) & 63;
    int nt = (tid >> 9) & 15;
    int ks = tid >> 13;
    int g = l >> 4, c = l & 15;
    int k = ks * 32 + g * 8 + p;
    int n = nt * 16 + c;
    float w = W[k * NDIM + n];
    unsigned short hi = f32_to_bf16_rne(w);
    unsigned short lo = f32_to_bf16_rne(w - bf16_to_f32(hi));
    wp[tid]         = hi;
    wp[65536 + tid] = lo;
}

// ---------------------------------------------------------------------------
// Main GEMM. Block: 256 threads (4 waves), tile = 128 tokens x 256 n (full N).
// Waves split N 4-way (64 cols each). A (x) staged via LDS in fragment-packed
// order (hi/lo bf16), double-buffered. B (W) fragments streamed from d_ws.
// ---------------------------------------------------------------------------

// LDS slot (ms, g, r): 8 bf16 (16B) = x_bf16[k = 8g+p][t = ms*16+r], p=0..7
// slot index = (ms*4 + g)*16 + r   (ms: 0..7, g: 0..3, r: 0..15) -> 512 slots

__device__ __forceinline__ void stage16(unsigned short* __restrict__ lh,
                                        unsigned short* __restrict__ ll,
                                        const float xr[16],
                                        int st_ms, int st_r, int st_kh) {
#pragma unroll
    for (int half = 0; half < 2; ++half) {
        int g_w = st_kh * 2 + half;
        ushort8 hv, lv;
#pragma unroll
        for (int p = 0; p < 8; ++p) {
            float f = xr[half * 8 + p];
            unsigned short h = f32_to_bf16_rne(f);
            unsigned short l = f32_to_bf16_rne(f - bf16_to_f32(h));
            hv[p] = h;
            lv[p] = l;
        }
        int slot = (st_ms * 4 + g_w) * 16 + st_r;
        *reinterpret_cast<ushort8*>(lh + slot * 8) = hv;
        *reinterpret_cast<ushort8*>(ll + slot * 8) = lv;
    }
}

__global__ __launch_bounds__(256, 2)
void xtw_gemm_kernel(const float* __restrict__ x,
                     const unsigned short* __restrict__ wp,
                     const float* __restrict__ bvec,
                     float* __restrict__ out) {
    __shared__ __align__(16) unsigned short lds[2][2][512 * 8];   // 32 KiB

    const int tid  = threadIdx.x;
    const int lane = tid & 63;
    const int wave = tid >> 6;        // 0..3 -> n-quadrant (64 cols)
    const int g = lane >> 4;          // k-group / D-row group
    const int r = lane & 15;          // A row offset / D col offset

    const int t0 = blockIdx.x * BM;

    // staging role: one token, 16 consecutive k per step
    const int st_t  = tid & 127;
    const int st_kh = tid >> 7;       // 0/1 -> k-half of the 32-k step
    const int st_ms = st_t >> 4;
    const int st_r  = st_t & 15;

    f32x4 acc[8][4];
#pragma unroll
    for (int ms = 0; ms < 8; ++ms)
#pragma unroll
        for (int nt = 0; nt < 4; ++nt)
            acc[ms][nt] = (f32x4){0.f, 0.f, 0.f, 0.f};

    // ---- prologue: stage k-step 0 ----
    {
        float xr[16];
#pragma unroll
        for (int j = 0; j < 16; ++j)
            xr[j] = x[(size_t)(st_kh * 16 + j) * TOKENS + t0 + st_t];
        stage16(&lds[0][0][0], &lds[0][1][0], xr, st_ms, st_r, st_kh);
    }
    __syncthreads();

    for (int ks = 0; ks < NSTEPS; ++ks) {
        const int cur = ks & 1;
        const int nxt = cur ^ 1;

        // issue next x tile loads early (latency hidden under MFMA/ds_read)
        float xn[16];
        if (ks < NSTEPS - 1) {
            const int kbase = (ks + 1) * BK + st_kh * 16;
#pragma unroll
            for (int j = 0; j < 16; ++j)
                xn[j] = x[(size_t)(kbase + j) * TOKENS + t0 + st_t];
        }

        // B fragments for this k-step (L1/L2-resident, prepacked)
        bf16x8 bhi[4], blo[4];
#pragma unroll
        for (int nt = 0; nt < 4; ++nt) {
            const int ntg = wave * 4 + nt;
            const size_t off = ((size_t)(ks * 16 + ntg) * 64 + lane) * 8;
            bhi[nt] = *reinterpret_cast<const bf16x8*>(wp + off);
            blo[nt] = *reinterpret_cast<const bf16x8*>(wp + 65536 + off);
        }

        const unsigned short* lh = &lds[cur][0][0];
        const unsigned short* ll = &lds[cur][1][0];

#pragma unroll
        for (int ms = 0; ms < 8; ++ms) {
            const int slot = (ms * 4 + g) * 16 + r;
            bf16x8 ahi = *reinterpret_cast<const bf16x8*>(lh + slot * 8);
            bf16x8 alo = *reinterpret_cast<const bf16x8*>(ll + slot * 8);
#pragma unroll
            for (int nt = 0; nt < 4; ++nt) {
                acc[ms][nt] = __builtin_amdgcn_mfma_f32_16x16x32_bf16(ahi, bhi[nt], acc[ms][nt], 0, 0, 0);
                acc[ms][nt] = __builtin_amdgcn_mfma_f32_16x16x32_bf16(ahi, blo[nt], acc[ms][nt], 0, 0, 0);
                acc[ms][nt] = __builtin_amdgcn_mfma_f32_16x16x32_bf16(alo, bhi[nt], acc[ms][nt], 0, 0, 0);
            }
        }

        if (ks < NSTEPS - 1) {
            stage16(&lds[nxt][0][0], &lds[nxt][1][0], xn, st_ms, st_r, st_kh);
        }
        __syncthreads();
    }

    // ---- epilogue: bias + store ----
    float bv[4];
#pragma unroll
    for (int nt = 0; nt < 4; ++nt)
        bv[nt] = bvec[wave * 64 + nt * 16 + r];

#pragma unroll
    for (int ms = 0; ms < 8; ++ms) {
#pragma unroll
        for (int nt = 0; nt < 4; ++nt) {
            const int n = wave * 64 + nt * 16 + r;
#pragma unroll
            for (int jj = 0; jj < 4; ++jj) {
                const int t = t0 + ms * 16 + g * 4 + jj;
                out[(size_t)t * NDIM + n] = acc[ms][nt][jj] + bv[nt];
            }
        }
    }
}

// ---------------------------------------------------------------------------
// Fallback (only if d_ws is unexpectedly tiny): plain f32, correct but slow.
// ---------------------------------------------------------------------------
__global__ void naive_xtw_kernel(const float* __restrict__ x,
                                 const float* __restrict__ W,
                                 const float* __restrict__ b,
                                 float* __restrict__ out) {
    int t = blockIdx.x;
    int n = threadIdx.x;
    float s = b[n];
    for (int k = 0; k < KDIM; ++k)
        s += x[(size_t)k * TOKENS + t] * W[k * NDIM + n];
    out[(size_t)t * NDIM + n] = s;
}

extern "C" void kernel_launch(void* const* d_in, const int* in_sizes, int n_in,
                              void* d_out, int out_size, void* d_ws, size_t ws_size,
                              hipStream_t stream) {
    const float* x = (const float*)d_in[0];
    const float* W = (const float*)d_in[1];
    const float* b = (const float*)d_in[2];
    float* out = (float*)d_out;

    if (ws_size >= (size_t)131072 * sizeof(unsigned short)) {
        unsigned short* wp = (unsigned short*)d_ws;
        prep_w_kernel<<<256, 256, 0, stream>>>(W, wp);
        xtw_gemm_kernel<<<TOKENS / BM, 256, 0, stream>>>(x, wp, b, out);
    } else {
        naive_xtw_kernel<<<TOKENS, 256, 0, stream>>>(x, W, b, out);
    }
}

// Round 2
// 267.514 us; speedup vs baseline: 1.0018x; 1.0018x over previous
//
#include <hip/hip_runtime.h>
#include <hip/hip_bf16.h>

// out[t,n] = sum_k x[k,t] * W[k,n] + b[n]
// x: [256, 131072] f32 (K-major), W: [256, 256] f32, b: [256] f32
// out: [131072, 256] f32
//
// Split-bf16 MFMA (hi*hi + hi*lo + lo*hi). Round-2 structure: full-K single
// staging per block (1 barrier), burst loads for max MLP, small acc tile.

#define TOKENS 131072
#define KDIM   256
#define NDIM   256
#define BM     64            // tokens per block
#define NKS    (KDIM / 32)   // 8 MFMA k-steps

typedef __bf16 bf16x8 __attribute__((ext_vector_type(8)));
typedef float  f32x4  __attribute__((ext_vector_type(4)));
typedef unsigned short ushort8 __attribute__((ext_vector_type(8)));

__device__ __forceinline__ unsigned short f32_to_bf16_rne(float f) {
    unsigned int u = __builtin_bit_cast(unsigned int, f);
    u += 0x7fffu + ((u >> 16) & 1u);   // round-to-nearest-even (finite inputs)
    return (unsigned short)(u >> 16);
}
__device__ __forceinline__ float bf16_to_f32(unsigned short h) {
    unsigned int u = ((unsigned int)h) << 16;
    return __builtin_bit_cast(float, u);
}

// ---------------------------------------------------------------------------
// Prep: pack W into B-fragment order, split into hi/lo bf16.
// wp (ushort): hi [0,65536), lo [65536,131072)
// element ((ks*16 + ntg)*64 + lane)*8 + p = W[ks*32 + (lane>>4)*8 + p][ntg*16 + (lane&15)]
// ---------------------------------------------------------------------------
__global__ void prep_w_kernel(const float* __restrict__ W, unsigned short* __restrict__ wp) {
    int tid = blockIdx.x * 256 + threadIdx.x;   // 0..65535
    int p  = tid & 7;
    int l  = (tid >> 3) & 63;
    int nt = (tid >> 9) & 15;
    int ks = tid >> 13;
    int g = l >> 4, c = l & 15;
    int k = ks * 32 + g * 8 + p;
    int n = nt * 16 + c;
    float w = W[k * NDIM + n];
    unsigned short hi = f32_to_bf16_rne(w);
    unsigned short lo = f32_to_bf16_rne(w - bf16_to_f32(hi));
    wp[tid]         = hi;
    wp[65536 + tid] = lo;
}

// ---------------------------------------------------------------------------
// Main GEMM. Block: 256 threads (4 waves). Tile: 64 tokens x full N=256.
// Stage ALL of K once (one barrier), then 8 barrier-free MFMA k-steps.
// LDS fragment-packed: slot(ks,g,ms,r) = ks*256 + g*64 + ms*16 + r, 8 bf16/slot.
//   holds x_bf16[k = ks*32 + g*8 + p][t = ms*16 + r]
// ---------------------------------------------------------------------------
__global__ __launch_bounds__(256, 2)
void xtw_gemm_kernel(const float* __restrict__ x,
                     const unsigned short* __restrict__ wp,
                     const float* __restrict__ bvec,
                     float* __restrict__ out) {
    __shared__ __align__(16) unsigned short lds_hi[BM * KDIM];  // 32 KiB
    __shared__ __align__(16) unsigned short lds_lo[BM * KDIM];  // 32 KiB

    const int tid  = threadIdx.x;
    const int lane = tid & 63;
    const int wave = tid >> 6;
    const int t0   = blockIdx.x * BM;

    // ---- staging: thread = (token = lane, k-quarter = wave) ----
    const int tok = lane;
    const int kq  = wave;

    float xr[64];
#pragma unroll
    for (int j = 0; j < 64; ++j)
        xr[j] = x[(size_t)(kq * 64 + j) * TOKENS + (t0 + tok)];

    const int ms_w = tok >> 4, r_w = tok & 15;
#pragma unroll
    for (int s = 0; s < 8; ++s) {           // thread's slot: k = kq*64 + 8s + p
        ushort8 hv, lv;
#pragma unroll
        for (int p = 0; p < 8; ++p) {
            float f = xr[s * 8 + p];
            unsigned short h = f32_to_bf16_rne(f);
            hv[p] = h;
            lv[p] = f32_to_bf16_rne(f - bf16_to_f32(h));
        }
        const int ks = kq * 2 + (s >> 2);
        const int g  = s & 3;
        const int slot = ks * 256 + g * 64 + ms_w * 16 + r_w;
        *reinterpret_cast<ushort8*>(lds_hi + slot * 8) = hv;
        *reinterpret_cast<ushort8*>(lds_lo + slot * 8) = lv;
    }
    __syncthreads();

    // ---- compute: wave owns n-quadrant [wave*64, wave*64+64) ----
    const int g = lane >> 4, r = lane & 15;

    f32x4 acc[4][4];
#pragma unroll
    for (int ms = 0; ms < 4; ++ms)
#pragma unroll
        for (int nt = 0; nt < 4; ++nt)
            acc[ms][nt] = (f32x4){0.f, 0.f, 0.f, 0.f};

#pragma unroll
    for (int ks = 0; ks < NKS; ++ks) {
        // B fragments for this k-step (L1/L2-resident; vmem queue is empty here)
        bf16x8 bhi[4], blo[4];
#pragma unroll
        for (int nt = 0; nt < 4; ++nt) {
            const int ntg = wave * 4 + nt;
            const size_t off = ((size_t)(ks * 16 + ntg) * 64 + lane) * 8;
            bhi[nt] = *reinterpret_cast<const bf16x8*>(wp + off);
            blo[nt] = *reinterpret_cast<const bf16x8*>(wp + 65536 + off);
        }
#pragma unroll
        for (int ms = 0; ms < 4; ++ms) {
            const int slot = ks * 256 + g * 64 + ms * 16 + r;
            bf16x8 ahi = *reinterpret_cast<const bf16x8*>(lds_hi + slot * 8);
            bf16x8 alo = *reinterpret_cast<const bf16x8*>(lds_lo + slot * 8);
#pragma unroll
            for (int nt = 0; nt < 4; ++nt) {
                acc[ms][nt] = __builtin_amdgcn_mfma_f32_16x16x32_bf16(ahi, bhi[nt], acc[ms][nt], 0, 0, 0);
                acc[ms][nt] = __builtin_amdgcn_mfma_f32_16x16x32_bf16(ahi, blo[nt], acc[ms][nt], 0, 0, 0);
                acc[ms][nt] = __builtin_amdgcn_mfma_f32_16x16x32_bf16(alo, bhi[nt], acc[ms][nt], 0, 0, 0);
            }
        }
    }

    // ---- epilogue: bias + nontemporal store (don't evict x from L3) ----
    float bv[4];
#pragma unroll
    for (int nt = 0; nt < 4; ++nt)
        bv[nt] = bvec[wave * 64 + nt * 16 + r];

#pragma unroll
    for (int ms = 0; ms < 4; ++ms) {
#pragma unroll
        for (int nt = 0; nt < 4; ++nt) {
            const int n = wave * 64 + nt * 16 + r;
#pragma unroll
            for (int jj = 0; jj < 4; ++jj) {
                const int t = t0 + ms * 16 + g * 4 + jj;
                __builtin_nontemporal_store(acc[ms][nt][jj] + bv[nt],
                                            &out[(size_t)t * NDIM + n]);
            }
        }
    }
}

// ---------------------------------------------------------------------------
// Fallback (only if d_ws is unexpectedly tiny): plain f32, correct but slow.
// ---------------------------------------------------------------------------
__global__ void naive_xtw_kernel(const float* __restrict__ x,
                                 const float* __restrict__ W,
                                 const float* __restrict__ b,
                                 float* __restrict__ out) {
    int t = blockIdx.x;
    int n = threadIdx.x;
    float s = b[n];
    for (int k = 0; k < KDIM; ++k)
        s += x[(size_t)k * TOKENS + t] * W[k * NDIM + n];
    out[(size_t)t * NDIM + n] = s;
}

extern "C" void kernel_launch(void* const* d_in, const int* in_sizes, int n_in,
                              void* d_out, int out_size, void* d_ws, size_t ws_size,
                              hipStream_t stream) {
    const float* x = (const float*)d_in[0];
    const float* W = (const float*)d_in[1];
    const float* b = (const float*)d_in[2];
    float* out = (float*)d_out;

    if (ws_size >= (size_t)131072 * sizeof(unsigned short)) {
        unsigned short* wp = (unsigned short*)d_ws;
        prep_w_kernel<<<256, 256, 0, stream>>>(W, wp);
        xtw_gemm_kernel<<<TOKENS / BM, 256, 0, stream>>>(x, wp, b, out);
    } else {
        naive_xtw_kernel<<<TOKENS, 256, 0, stream>>>(x, W, b, out);
    }
}